// Round 1
// baseline (656.825 us; speedup 1.0000x reference)
//
#include <hip/hip_runtime.h>
#include <math.h>

// Problem constants
#define BB 2
#define TT 2048
#define CC 1024
#define HH 16
#define DD 64
#define MM (BB*TT)      // 4096 rows
#define LCH 128         // chunk length
#define NCH (TT/LCH)    // 16 chunks
#define BHH (BB*HH)     // 32

// Output layout in d_out (floats):
//   out      : [0, 4194304)            (B,T,C)
//   new_kv   : [4194304, 4325376)      (B,H,D,D)
//   new_ksum : [4325376, 4327424)      (B,H,D)
#define OUT_OFF_KV   4194304
#define OUT_OFF_KSUM 4325376

__device__ __forceinline__ float fmap(float x) {
    return x > 0.0f ? x + 1.0f : expf(x);
}

// C[m,n] = sum_k A[m,k] * W[n,k]   (A: MMxCC, W: CCxCC row-major)
// MODE 0: apply fmap, write to (B,H,T,D) layout
// MODE 1: no fmap, write to (B,H,T,D) layout
// MODE 2: add bias, write row-major (B,T,C) (final output)
template<int MODE>
__global__ __launch_bounds__(256)
void lca_gemm(const float* __restrict__ A, const float* __restrict__ W,
              const float* __restrict__ bias, float* __restrict__ out)
{
    __shared__ float As[16][64];
    __shared__ float Bs[16][64];
    const int bm0 = blockIdx.y * 64;
    const int bn0 = blockIdx.x * 64;
    const int tid = threadIdx.x;
    const int tm = tid >> 4;   // 0..15
    const int tn = tid & 15;   // 0..15

    float acc[4][4] = {};

    for (int k0 = 0; k0 < CC; k0 += 16) {
        // stage tiles: each thread loads one float4 of A and of W
        {
            const int r  = tid >> 2;        // 0..63
            const int kk = (tid & 3) * 4;   // 0,4,8,12
            const float4 av = *(const float4*)(&A[(size_t)(bm0 + r) * CC + k0 + kk]);
            As[kk+0][r] = av.x; As[kk+1][r] = av.y; As[kk+2][r] = av.z; As[kk+3][r] = av.w;
            const float4 bv = *(const float4*)(&W[(size_t)(bn0 + r) * CC + k0 + kk]);
            Bs[kk+0][r] = bv.x; Bs[kk+1][r] = bv.y; Bs[kk+2][r] = bv.z; Bs[kk+3][r] = bv.w;
        }
        __syncthreads();
        #pragma unroll
        for (int kk = 0; kk < 16; ++kk) {
            const float4 a = *(const float4*)(&As[kk][tm*4]);
            const float4 b = *(const float4*)(&Bs[kk][tn*4]);
            acc[0][0] += a.x*b.x; acc[0][1] += a.x*b.y; acc[0][2] += a.x*b.z; acc[0][3] += a.x*b.w;
            acc[1][0] += a.y*b.x; acc[1][1] += a.y*b.y; acc[1][2] += a.y*b.z; acc[1][3] += a.y*b.w;
            acc[2][0] += a.z*b.x; acc[2][1] += a.z*b.y; acc[2][2] += a.z*b.z; acc[2][3] += a.z*b.w;
            acc[3][0] += a.w*b.x; acc[3][1] += a.w*b.y; acc[3][2] += a.w*b.z; acc[3][3] += a.w*b.w;
        }
        __syncthreads();
    }

    #pragma unroll
    for (int i = 0; i < 4; ++i) {
        const int m = bm0 + tm*4 + i;
        const int n0 = bn0 + tn*4;
        float4 vv = make_float4(acc[i][0], acc[i][1], acc[i][2], acc[i][3]);
        if (MODE == 0) {
            vv.x = fmap(vv.x); vv.y = fmap(vv.y); vv.z = fmap(vv.z); vv.w = fmap(vv.w);
        }
        if (MODE == 2) {
            const float4 bb4 = *(const float4*)(&bias[n0]);
            vv.x += bb4.x; vv.y += bb4.y; vv.z += bb4.z; vv.w += bb4.w;
            *(float4*)(&out[(size_t)m * CC + n0]) = vv;
        } else {
            // (B,H,T,D): b=m>>11, t=m&2047, h=n0>>6, d=n0&63
            const int b = m >> 11, t = m & (TT-1);
            const int h = n0 >> 6, d = n0 & (DD-1);
            *(float4*)(&out[(((size_t)(b*HH + h) * TT + t) * DD) + d]) = vv;
        }
    }
}

// Pass 1: per (b,h,chunk): local S[d][e] = sum_t kp[t,d]*v[t,e], local ksum[d]
__global__ __launch_bounds__(256)
void lca_pass1(const float* __restrict__ kp, const float* __restrict__ v,
               float* __restrict__ Sloc, float* __restrict__ ksloc)
{
    __shared__ float kps[LCH][DD];
    __shared__ float vs[LCH][DD];
    const int c = blockIdx.x, bh = blockIdx.y;
    const int tid = threadIdx.x;
    const size_t base = ((size_t)bh * TT + (size_t)c * LCH) * DD;

    for (int idx = tid*4; idx < LCH*DD; idx += 1024) {
        *(float4*)(&kps[0][0] + idx) = *(const float4*)(&kp[base + idx]);
        *(float4*)(&vs[0][0]  + idx) = *(const float4*)(&v[base + idx]);
    }
    __syncthreads();

    const int d0 = (tid >> 4) * 4;   // 0..60
    const int e0 = (tid & 15) * 4;   // 0..60
    float s[4][4] = {};
    for (int t = 0; t < LCH; ++t) {
        const float4 kv = *(const float4*)(&kps[t][d0]);
        const float4 vv = *(const float4*)(&vs[t][e0]);
        s[0][0] += kv.x*vv.x; s[0][1] += kv.x*vv.y; s[0][2] += kv.x*vv.z; s[0][3] += kv.x*vv.w;
        s[1][0] += kv.y*vv.x; s[1][1] += kv.y*vv.y; s[1][2] += kv.y*vv.z; s[1][3] += kv.y*vv.w;
        s[2][0] += kv.z*vv.x; s[2][1] += kv.z*vv.y; s[2][2] += kv.z*vv.z; s[2][3] += kv.z*vv.w;
        s[3][0] += kv.w*vv.x; s[3][1] += kv.w*vv.y; s[3][2] += kv.w*vv.z; s[3][3] += kv.w*vv.w;
    }
    float* Sout = &Sloc[((size_t)bh * NCH + c) * (DD*DD)];
    #pragma unroll
    for (int i = 0; i < 4; ++i)
        *(float4*)(&Sout[(size_t)(d0+i)*DD + e0]) = make_float4(s[i][0], s[i][1], s[i][2], s[i][3]);

    if (tid < DD) {
        float ks = 0.0f;
        for (int t = 0; t < LCH; ++t) ks += kps[t][tid];
        ksloc[((size_t)bh * NCH + c) * DD + tid] = ks;
    }
}

// Pass 2: per (b,h): sequential exclusive scan over chunks (in place);
// writes final inclusive state to d_out (new_kv, new_ksum).
__global__ __launch_bounds__(256)
void lca_pass2(float* __restrict__ Sloc, float* __restrict__ ksloc,
               float* __restrict__ out)
{
    const int bh = blockIdx.x;
    const int tid = threadIdx.x;
    const int d0 = (tid >> 4) * 4;
    const int e0 = (tid & 15) * 4;

    float4 run[4];
    #pragma unroll
    for (int i = 0; i < 4; ++i) run[i] = make_float4(0,0,0,0);

    for (int c = 0; c < NCH; ++c) {
        float* Sp = &Sloc[((size_t)bh * NCH + c) * (DD*DD)];
        #pragma unroll
        for (int i = 0; i < 4; ++i) {
            float4* p = (float4*)(&Sp[(size_t)(d0+i)*DD + e0]);
            const float4 tmp = *p;
            *p = run[i];
            run[i].x += tmp.x; run[i].y += tmp.y; run[i].z += tmp.z; run[i].w += tmp.w;
        }
    }
    float* nkv = out + OUT_OFF_KV + (size_t)bh * (DD*DD);
    #pragma unroll
    for (int i = 0; i < 4; ++i)
        *(float4*)(&nkv[(size_t)(d0+i)*DD + e0]) = run[i];

    if (tid < DD) {
        float r = 0.0f;
        for (int c = 0; c < NCH; ++c) {
            float* kptr = &ksloc[((size_t)bh * NCH + c) * DD + tid];
            const float tmp = *kptr;
            *kptr = r;
            r += tmp;
        }
        out[OUT_OFF_KSUM + (size_t)bh * DD + tid] = r;
    }
}

// Pass 3: per (b,h,chunk): y[t] = (qp[t]@P + sum_{t'<=t} (qp[t].kp[t']) v[t']) / den
__global__ __launch_bounds__(256)
void lca_pass3(const float* __restrict__ qp, const float* __restrict__ kp,
               const float* __restrict__ v, const float* __restrict__ Sloc,
               const float* __restrict__ ksloc, float* __restrict__ y)
{
    __shared__ float qps[LCH][DD];
    __shared__ float kps[LCH][DD];
    __shared__ float vs[LCH][DD];
    __shared__ float Ps[DD][DD];
    __shared__ float pks[DD];

    const int c = blockIdx.x, bh = blockIdx.y;
    const int tid = threadIdx.x;
    const size_t base = ((size_t)bh * TT + (size_t)c * LCH) * DD;

    for (int idx = tid*4; idx < LCH*DD; idx += 1024) {
        *(float4*)(&qps[0][0] + idx) = *(const float4*)(&qp[base + idx]);
        *(float4*)(&kps[0][0] + idx) = *(const float4*)(&kp[base + idx]);
        *(float4*)(&vs[0][0]  + idx) = *(const float4*)(&v[base + idx]);
    }
    {
        const float* Sp = &Sloc[((size_t)bh * NCH + c) * (DD*DD)];
        for (int idx = tid*4; idx < DD*DD; idx += 1024)
            *(float4*)(&Ps[0][0] + idx) = *(const float4*)(&Sp[idx]);
        if (tid < DD) pks[tid] = ksloc[((size_t)bh * NCH + c) * DD + tid];
    }
    __syncthreads();

    const int t  = tid >> 1;          // 0..127
    const int e0 = (tid & 1) * 32;    // 0 or 32

    float num[32];
    #pragma unroll
    for (int j = 0; j < 32; ++j) num[j] = 0.0f;
    float den = 1e-6f;

    // inter-chunk: qp[t] @ P  and qp[t] . pksum
    for (int d = 0; d < DD; ++d) {
        const float qv = qps[t][d];
        den += qv * pks[d];
        #pragma unroll
        for (int j = 0; j < 32; j += 4) {
            const float4 pv = *(const float4*)(&Ps[d][e0 + j]);
            num[j+0] += qv * pv.x; num[j+1] += qv * pv.y;
            num[j+2] += qv * pv.z; num[j+3] += qv * pv.w;
        }
    }
    // intra-chunk causal part
    for (int tp = 0; tp <= t; ++tp) {
        float a = 0.0f;
        #pragma unroll
        for (int d = 0; d < DD; d += 4) {
            const float4 qv = *(const float4*)(&qps[t][d]);
            const float4 kv = *(const float4*)(&kps[tp][d]);
            a += qv.x*kv.x + qv.y*kv.y + qv.z*kv.z + qv.w*kv.w;
        }
        den += a;
        #pragma unroll
        for (int j = 0; j < 32; j += 4) {
            const float4 vv = *(const float4*)(&vs[tp][e0 + j]);
            num[j+0] += a * vv.x; num[j+1] += a * vv.y;
            num[j+2] += a * vv.z; num[j+3] += a * vv.w;
        }
    }

    const float inv = 1.0f / den;
    const int b = bh >> 4, h = bh & (HH-1);
    float* yrow = &y[((size_t)(b*TT) + (size_t)c*LCH + t) * CC + h*DD + e0];
    #pragma unroll
    for (int j = 0; j < 32; j += 4) {
        *(float4*)(&yrow[j]) = make_float4(num[j]*inv, num[j+1]*inv, num[j+2]*inv, num[j+3]*inv);
    }
}

extern "C" void kernel_launch(void* const* d_in, const int* in_sizes, int n_in,
                              void* d_out, int out_size, void* d_ws, size_t ws_size,
                              hipStream_t stream) {
    const float* x  = (const float*)d_in[0];
    const float* Wq = (const float*)d_in[1];
    const float* Wk = (const float*)d_in[2];
    const float* Wv = (const float*)d_in[3];
    const float* Wp = (const float*)d_in[4];
    const float* bp = (const float*)d_in[5];
    float* out = (float*)d_out;
    float* ws  = (float*)d_ws;

    // workspace layout (floats)
    float* qp  = ws;                  // 4194304
    float* kp  = ws + 4194304;        // 4194304
    float* v   = ws + 8388608;        // 4194304
    float* y   = ws + 12582912;       // 4194304
    float* Sl  = ws + 16777216;       // 2*16*16*4096 = 2097152
    float* ksl = ws + 18874368;       // 32768

    const dim3 gg(CC/64, MM/64);
    lca_gemm<0><<<gg, 256, 0, stream>>>(x, Wq, nullptr, qp);
    lca_gemm<0><<<gg, 256, 0, stream>>>(x, Wk, nullptr, kp);
    lca_gemm<1><<<gg, 256, 0, stream>>>(x, Wv, nullptr, v);

    lca_pass1<<<dim3(NCH, BHH), 256, 0, stream>>>(kp, v, Sl, ksl);
    lca_pass2<<<BHH, 256, 0, stream>>>(Sl, ksl, out);
    lca_pass3<<<dim3(NCH, BHH), 256, 0, stream>>>(qp, kp, v, Sl, ksl, y);

    lca_gemm<2><<<gg, 256, 0, stream>>>(y, Wp, bp, out);
}

// Round 2
// 253.361 us; speedup vs baseline: 2.5924x; 2.5924x over previous
//
#include <hip/hip_runtime.h>
#include <math.h>

// Problem constants
#define BB 2
#define TT 2048
#define CC 1024
#define HH 16
#define DD 64
#define MM (BB*TT)      // 4096 rows
#define LCH 128         // chunk length
#define NCH (TT/LCH)    // 16 chunks
#define BHH (BB*HH)     // 32

#define OUT_OFF_KV   4194304
#define OUT_OFF_KSUM 4325376

typedef unsigned int u32;
typedef __attribute__((ext_vector_type(8))) short s16x8;
typedef __attribute__((ext_vector_type(8))) unsigned short us8;
typedef __attribute__((ext_vector_type(4))) float f32x4;

__device__ __forceinline__ float fmap(float x) {
    return x > 0.0f ? x + 1.0f : expf(x);
}

__device__ __forceinline__ unsigned short bf16r(float f) {
    u32 u = __float_as_uint(f);
    u += 0x7fffu + ((u >> 16) & 1u);
    return (unsigned short)(u >> 16);
}

__device__ __forceinline__ void gload16(const void* g, void* l) {
    __builtin_amdgcn_global_load_lds(
        (const __attribute__((address_space(1))) u32*)g,
        (__attribute__((address_space(3))) u32*)l, 16, 0, 0);
}

// fp32 -> bf16 cast, 8 elems/thread
__global__ __launch_bounds__(256)
void f2bf8(const float* __restrict__ in, unsigned short* __restrict__ out, int n8)
{
    const int i = blockIdx.x * 256 + threadIdx.x;
    if (i >= n8) return;
    const float4 a = ((const float4*)in)[i*2];
    const float4 b = ((const float4*)in)[i*2 + 1];
    us8 p;
    p[0]=bf16r(a.x); p[1]=bf16r(a.y); p[2]=bf16r(a.z); p[3]=bf16r(a.w);
    p[4]=bf16r(b.x); p[5]=bf16r(b.y); p[6]=bf16r(b.z); p[7]=bf16r(b.w);
    ((us8*)out)[i] = p;
}

// bf16 MFMA GEMM, m97 structure: 128x128 tile, BK=32, 4 waves (2x2), 16x16x32 MFMA.
// C[m,n] = sum_k A[m,k]*W[n,k]  (A: MMx1024 bf16 row-major, W: 1024x1024 bf16 row-major)
// MODE 0: fmap epilogue -> (B,H,T,D) fp32 ;  MODE 1: plain -> (B,H,T,D) fp32
// MODE 2: +bias -> row-major (B,T,C) fp32
template<int MODE>
__global__ __launch_bounds__(256)
void lca_gemm_bf(const unsigned short* __restrict__ A, const unsigned short* __restrict__ W,
                 const float* __restrict__ bias, float* __restrict__ out)
{
    __shared__ short As[128*32];
    __shared__ short Bs[128*32];
    const int tid  = threadIdx.x;
    const int lane = tid & 63;
    const int wid  = tid >> 6;
    const int bm0 = blockIdx.y * 128;
    const int bn0 = blockIdx.x * 128;
    const int wm = wid >> 1, wn = wid & 1;

    // staging indices: seg = wid*2 + j; row = seg*16 + lane/4; kcol = (lane&3)*8
    const int rs = wid*32 + (lane >> 2);
    const int kc = (lane & 3) * 8;

    f32x4 acc[4][4];
    #pragma unroll
    for (int i = 0; i < 4; ++i)
        #pragma unroll
        for (int j = 0; j < 4; ++j)
            acc[i][j] = (f32x4){0.f, 0.f, 0.f, 0.f};

    const int rA = wm*64 + (lane & 15);
    const int rB = wn*64 + (lane & 15);
    const int kk = (lane >> 4) * 8;

    for (int k0 = 0; k0 < CC; k0 += 32) {
        #pragma unroll
        for (int j = 0; j < 2; ++j) {
            gload16(A + (size_t)(bm0 + rs + j*16) * CC + k0 + kc, &As[wid*1024 + j*512]);
            gload16(W + (size_t)(bn0 + rs + j*16) * CC + k0 + kc, &Bs[wid*1024 + j*512]);
        }
        __syncthreads();

        s16x8 af[4], bf[4];
        #pragma unroll
        for (int mi = 0; mi < 4; ++mi) af[mi] = *(const s16x8*)(&As[(rA + mi*16)*32 + kk]);
        #pragma unroll
        for (int ni = 0; ni < 4; ++ni) bf[ni] = *(const s16x8*)(&Bs[(rB + ni*16)*32 + kk]);
        #pragma unroll
        for (int mi = 0; mi < 4; ++mi)
            #pragma unroll
            for (int ni = 0; ni < 4; ++ni)
                acc[mi][ni] = __builtin_amdgcn_mfma_f32_16x16x32_bf16(af[mi], bf[ni], acc[mi][ni], 0, 0, 0);
        __syncthreads();
    }

    // epilogue: lane holds col = lane&15, rows (lane>>4)*4 + r
    #pragma unroll
    for (int mi = 0; mi < 4; ++mi) {
        #pragma unroll
        for (int ni = 0; ni < 4; ++ni) {
            const int col = bn0 + wn*64 + ni*16 + (lane & 15);
            const int rb  = bm0 + wm*64 + mi*16 + (lane >> 4)*4;
            #pragma unroll
            for (int r = 0; r < 4; ++r) {
                float val = acc[mi][ni][r];
                const int m = rb + r;
                if (MODE == 0) val = fmap(val);
                if (MODE == 2) {
                    val += bias[col];
                    out[(size_t)m * CC + col] = val;
                } else {
                    const int b = m >> 11, t = m & (TT-1);
                    const int h = col >> 6, d = col & (DD-1);
                    out[(((size_t)(b*HH + h) * TT + t) * DD) + d] = val;
                }
            }
        }
    }
}

// Pass 1: per (b,h,chunk): local S[d][e] = sum_t kp[t,d]*v[t,e], local ksum[d]
__global__ __launch_bounds__(256)
void lca_pass1(const float* __restrict__ kp, const float* __restrict__ v,
               float* __restrict__ Sloc, float* __restrict__ ksloc)
{
    __shared__ float kps[LCH][DD];
    __shared__ float vs[LCH][DD];
    const int c = blockIdx.x, bh = blockIdx.y;
    const int tid = threadIdx.x;
    const size_t base = ((size_t)bh * TT + (size_t)c * LCH) * DD;

    for (int idx = tid*4; idx < LCH*DD; idx += 1024) {
        *(float4*)(&kps[0][0] + idx) = *(const float4*)(&kp[base + idx]);
        *(float4*)(&vs[0][0]  + idx) = *(const float4*)(&v[base + idx]);
    }
    __syncthreads();

    const int d0 = (tid >> 4) * 4;
    const int e0 = (tid & 15) * 4;
    float s[4][4] = {};
    for (int t = 0; t < LCH; ++t) {
        const float4 kv = *(const float4*)(&kps[t][d0]);
        const float4 vv = *(const float4*)(&vs[t][e0]);
        s[0][0] += kv.x*vv.x; s[0][1] += kv.x*vv.y; s[0][2] += kv.x*vv.z; s[0][3] += kv.x*vv.w;
        s[1][0] += kv.y*vv.x; s[1][1] += kv.y*vv.y; s[1][2] += kv.y*vv.z; s[1][3] += kv.y*vv.w;
        s[2][0] += kv.z*vv.x; s[2][1] += kv.z*vv.y; s[2][2] += kv.z*vv.z; s[2][3] += kv.z*vv.w;
        s[3][0] += kv.w*vv.x; s[3][1] += kv.w*vv.y; s[3][2] += kv.w*vv.z; s[3][3] += kv.w*vv.w;
    }
    float* Sout = &Sloc[((size_t)bh * NCH + c) * (DD*DD)];
    #pragma unroll
    for (int i = 0; i < 4; ++i)
        *(float4*)(&Sout[(size_t)(d0+i)*DD + e0]) = make_float4(s[i][0], s[i][1], s[i][2], s[i][3]);

    if (tid < DD) {
        float ks = 0.0f;
        for (int t = 0; t < LCH; ++t) ks += kps[t][tid];
        ksloc[((size_t)bh * NCH + c) * DD + tid] = ks;
    }
}

// Pass 2: per (b,h): sequential exclusive scan over chunks (in place);
// writes final inclusive state to d_out (new_kv, new_ksum).
__global__ __launch_bounds__(256)
void lca_pass2(float* __restrict__ Sloc, float* __restrict__ ksloc,
               float* __restrict__ out)
{
    const int bh = blockIdx.x;
    const int tid = threadIdx.x;
    const int d0 = (tid >> 4) * 4;
    const int e0 = (tid & 15) * 4;

    float4 run[4];
    #pragma unroll
    for (int i = 0; i < 4; ++i) run[i] = make_float4(0,0,0,0);

    for (int c = 0; c < NCH; ++c) {
        float* Sp = &Sloc[((size_t)bh * NCH + c) * (DD*DD)];
        #pragma unroll
        for (int i = 0; i < 4; ++i) {
            float4* p = (float4*)(&Sp[(size_t)(d0+i)*DD + e0]);
            const float4 tmp = *p;
            *p = run[i];
            run[i].x += tmp.x; run[i].y += tmp.y; run[i].z += tmp.z; run[i].w += tmp.w;
        }
    }
    float* nkv = out + OUT_OFF_KV + (size_t)bh * (DD*DD);
    #pragma unroll
    for (int i = 0; i < 4; ++i)
        *(float4*)(&nkv[(size_t)(d0+i)*DD + e0]) = run[i];

    if (tid < DD) {
        float r = 0.0f;
        for (int c = 0; c < NCH; ++c) {
            float* kptr = &ksloc[((size_t)bh * NCH + c) * DD + tid];
            const float tmp = *kptr;
            *kptr = r;
            r += tmp;
        }
        out[OUT_OFF_KSUM + (size_t)bh * DD + tid] = r;
    }
}

// Pass 3: per (b,h,chunk): y[t] = (qp[t]@P + sum_{t'<=t} (qp[t].kp[t']) v[t']) / den
// writes y as bf16 (row-major (B,T,C)) for the final MFMA GEMM
__global__ __launch_bounds__(256)
void lca_pass3(const float* __restrict__ qp, const float* __restrict__ kp,
               const float* __restrict__ v, const float* __restrict__ Sloc,
               const float* __restrict__ ksloc, unsigned short* __restrict__ ybf)
{
    __shared__ float qps[LCH][DD];
    __shared__ float kps[LCH][DD];
    __shared__ float vs[LCH][DD];
    __shared__ float Ps[DD][DD];
    __shared__ float pks[DD];

    const int c = blockIdx.x, bh = blockIdx.y;
    const int tid = threadIdx.x;
    const size_t base = ((size_t)bh * TT + (size_t)c * LCH) * DD;

    for (int idx = tid*4; idx < LCH*DD; idx += 1024) {
        *(float4*)(&qps[0][0] + idx) = *(const float4*)(&qp[base + idx]);
        *(float4*)(&kps[0][0] + idx) = *(const float4*)(&kp[base + idx]);
        *(float4*)(&vs[0][0]  + idx) = *(const float4*)(&v[base + idx]);
    }
    {
        const float* Sp = &Sloc[((size_t)bh * NCH + c) * (DD*DD)];
        for (int idx = tid*4; idx < DD*DD; idx += 1024)
            *(float4*)(&Ps[0][0] + idx) = *(const float4*)(&Sp[idx]);
        if (tid < DD) pks[tid] = ksloc[((size_t)bh * NCH + c) * DD + tid];
    }
    __syncthreads();

    const int t  = tid >> 1;
    const int e0 = (tid & 1) * 32;

    float num[32];
    #pragma unroll
    for (int j = 0; j < 32; ++j) num[j] = 0.0f;
    float den = 1e-6f;

    for (int d = 0; d < DD; ++d) {
        const float qv = qps[t][d];
        den += qv * pks[d];
        #pragma unroll
        for (int j = 0; j < 32; j += 4) {
            const float4 pv = *(const float4*)(&Ps[d][e0 + j]);
            num[j+0] += qv * pv.x; num[j+1] += qv * pv.y;
            num[j+2] += qv * pv.z; num[j+3] += qv * pv.w;
        }
    }
    for (int tp = 0; tp <= t; ++tp) {
        float a = 0.0f;
        #pragma unroll
        for (int d = 0; d < DD; d += 4) {
            const float4 qv = *(const float4*)(&qps[t][d]);
            const float4 kv = *(const float4*)(&kps[tp][d]);
            a += qv.x*kv.x + qv.y*kv.y + qv.z*kv.z + qv.w*kv.w;
        }
        den += a;
        #pragma unroll
        for (int j = 0; j < 32; j += 4) {
            const float4 vv = *(const float4*)(&vs[tp][e0 + j]);
            num[j+0] += a * vv.x; num[j+1] += a * vv.y;
            num[j+2] += a * vv.z; num[j+3] += a * vv.w;
        }
    }

    const float inv = 1.0f / den;
    const int b = bh >> 4, h = bh & (HH-1);
    unsigned short* yrow = &ybf[((size_t)(b*TT) + (size_t)c*LCH + t) * CC + h*DD + e0];
    #pragma unroll
    for (int g = 0; g < 4; ++g) {
        us8 p;
        #pragma unroll
        for (int j = 0; j < 8; ++j) p[j] = bf16r(num[g*8 + j] * inv);
        *(us8*)(&yrow[g*8]) = p;
    }
}

extern "C" void kernel_launch(void* const* d_in, const int* in_sizes, int n_in,
                              void* d_out, int out_size, void* d_ws, size_t ws_size,
                              hipStream_t stream) {
    const float* x  = (const float*)d_in[0];
    const float* Wq = (const float*)d_in[1];
    const float* Wk = (const float*)d_in[2];
    const float* Wv = (const float*)d_in[3];
    const float* Wp = (const float*)d_in[4];
    const float* bp = (const float*)d_in[5];
    float* out = (float*)d_out;
    char* ws = (char*)d_ws;

    // workspace layout (bytes)
    float* qp           = (float*)(ws + 0);              // 16 MB
    float* kp           = (float*)(ws + 16777216);       // 16 MB
    float* v            = (float*)(ws + 33554432);       // 16 MB
    float* Sl           = (float*)(ws + 50331648);       // 8 MB
    float* ksl          = (float*)(ws + 58720256);       // 128 KB
    unsigned short* xbf = (unsigned short*)(ws + 58851328); // 8 MB
    unsigned short* Wbf = (unsigned short*)(ws + 67239936); // 2 MB
    unsigned short* ybf = (unsigned short*)(ws + 69337088); // 8 MB

    const dim3 gg(CC/128, MM/128);

    f2bf8<<<MM*CC/8/256, 256, 0, stream>>>(x, xbf, MM*CC/8);

    f2bf8<<<CC*CC/8/256, 256, 0, stream>>>(Wq, Wbf, CC*CC/8);
    lca_gemm_bf<0><<<gg, 256, 0, stream>>>(xbf, Wbf, nullptr, qp);
    f2bf8<<<CC*CC/8/256, 256, 0, stream>>>(Wk, Wbf, CC*CC/8);
    lca_gemm_bf<0><<<gg, 256, 0, stream>>>(xbf, Wbf, nullptr, kp);
    f2bf8<<<CC*CC/8/256, 256, 0, stream>>>(Wv, Wbf, CC*CC/8);
    lca_gemm_bf<1><<<gg, 256, 0, stream>>>(xbf, Wbf, nullptr, v);

    lca_pass1<<<dim3(NCH, BHH), 256, 0, stream>>>(kp, v, Sl, ksl);
    lca_pass2<<<BHH, 256, 0, stream>>>(Sl, ksl, out);
    lca_pass3<<<dim3(NCH, BHH), 256, 0, stream>>>(qp, kp, v, Sl, ksl, ybf);

    f2bf8<<<CC*CC/8/256, 256, 0, stream>>>(Wp, Wbf, CC*CC/8);
    lca_gemm_bf<2><<<gg, 256, 0, stream>>>(ybf, Wbf, bp, out);
}

// Round 3
// 164.405 us; speedup vs baseline: 3.9952x; 1.5411x over previous
//
#include <hip/hip_runtime.h>
#include <math.h>

#define BB 2
#define TT 2048
#define CC 1024
#define HH 16
#define DD 64
#define MM (BB*TT)
#define LCH 128
#define NCH (TT/LCH)
#define BHH (BB*HH)

#define OUT_OFF_KV   4194304
#define OUT_OFF_KSUM 4325376
#define MB 1048576

typedef unsigned int u32;
typedef unsigned short u16;
typedef __attribute__((ext_vector_type(8))) short s16x8;
typedef __attribute__((ext_vector_type(8))) unsigned short us8;
typedef __attribute__((ext_vector_type(4))) float f32x4;

__device__ __forceinline__ float fmap(float x) {
    return x > 0.0f ? x + 1.0f : expf(x);
}
__device__ __forceinline__ u16 bf16r(float f) {
    u32 u = __float_as_uint(f);
    u += 0x7fffu + ((u >> 16) & 1u);
    return (u16)(u >> 16);
}
__device__ __forceinline__ float bf2f(u16 u) {
    return __uint_as_float(((u32)u) << 16);
}
__device__ __forceinline__ void gload16(const void* g, void* l) {
    __builtin_amdgcn_global_load_lds(
        (const __attribute__((address_space(1))) u32*)g,
        (__attribute__((address_space(3))) u32*)l, 16, 0, 0);
}

// fp32 -> bf16 cast, 8 elems/thread
__global__ __launch_bounds__(256)
void f2bf8(const float* __restrict__ in, u16* __restrict__ out, int n8)
{
    const int i = blockIdx.x * 256 + threadIdx.x;
    if (i >= n8) return;
    const float4 a = ((const float4*)in)[i*2];
    const float4 b = ((const float4*)in)[i*2 + 1];
    us8 p;
    p[0]=bf16r(a.x); p[1]=bf16r(a.y); p[2]=bf16r(a.z); p[3]=bf16r(a.w);
    p[4]=bf16r(b.x); p[5]=bf16r(b.y); p[6]=bf16r(b.z); p[7]=bf16r(b.w);
    ((us8*)out)[i] = p;
}

// bf16 MFMA GEMM: C[m,n] = sum_k A[m,k]*W[n,k]
// MODE 0: fmap -> o_rm bf16 (B,H,T,D)                       (Q)
// MODE 3: fmap -> o_rm bf16 (B,H,T,D) + o_tr bf16 [bh][c][d][t]  (K)
// MODE 1: plain -> o_tr only                                 (V)
// MODE 2: +bias -> fp32 row-major (B,T,C)                    (final)
template<int MODE>
__global__ __launch_bounds__(256)
void lca_gemm_bf(const u16* __restrict__ A, const u16* __restrict__ W,
                 const float* __restrict__ bias, float* __restrict__ outf,
                 u16* __restrict__ o_rm, u16* __restrict__ o_tr)
{
    __shared__ short As[128*32];
    __shared__ short Bs[128*32];
    const int tid  = threadIdx.x;
    const int lane = tid & 63;
    const int wid  = tid >> 6;
    const int bm0 = blockIdx.y * 128;
    const int bn0 = blockIdx.x * 128;
    const int wm = wid >> 1, wn = wid & 1;

    const int rs = wid*32 + (lane >> 2);
    const int kc = (lane & 3) * 8;

    f32x4 acc[4][4];
    #pragma unroll
    for (int i = 0; i < 4; ++i)
        #pragma unroll
        for (int j = 0; j < 4; ++j)
            acc[i][j] = (f32x4){0.f, 0.f, 0.f, 0.f};

    const int rA = wm*64 + (lane & 15);
    const int rB = wn*64 + (lane & 15);
    const int kk = (lane >> 4) * 8;

    for (int k0 = 0; k0 < CC; k0 += 32) {
        #pragma unroll
        for (int j = 0; j < 2; ++j) {
            gload16(A + (size_t)(bm0 + rs + j*16) * CC + k0 + kc, &As[wid*1024 + j*512]);
            gload16(W + (size_t)(bn0 + rs + j*16) * CC + k0 + kc, &Bs[wid*1024 + j*512]);
        }
        __syncthreads();

        s16x8 af[4], bf[4];
        #pragma unroll
        for (int mi = 0; mi < 4; ++mi) af[mi] = *(const s16x8*)(&As[(rA + mi*16)*32 + kk]);
        #pragma unroll
        for (int ni = 0; ni < 4; ++ni) bf[ni] = *(const s16x8*)(&Bs[(rB + ni*16)*32 + kk]);
        #pragma unroll
        for (int mi = 0; mi < 4; ++mi)
            #pragma unroll
            for (int ni = 0; ni < 4; ++ni)
                acc[mi][ni] = __builtin_amdgcn_mfma_f32_16x16x32_bf16(af[mi], bf[ni], acc[mi][ni], 0, 0, 0);
        __syncthreads();
    }

    #pragma unroll
    for (int mi = 0; mi < 4; ++mi) {
        #pragma unroll
        for (int ni = 0; ni < 4; ++ni) {
            const int col = bn0 + wn*64 + ni*16 + (lane & 15);
            const int rb  = bm0 + wm*64 + mi*16 + (lane >> 4)*4;
            if (MODE == 2) {
                const float bb = bias[col];
                #pragma unroll
                for (int r = 0; r < 4; ++r)
                    outf[(size_t)(rb + r) * CC + col] = acc[mi][ni][r] + bb;
            } else {
                const int h = col >> 6, d = col & (DD-1);
                const int b = rb >> 11, t0 = rb & (TT-1);
                u16 bv[4];
                #pragma unroll
                for (int r = 0; r < 4; ++r) {
                    float val = acc[mi][ni][r];
                    if (MODE != 1) val = fmap(val);
                    bv[r] = bf16r(val);
                }
                if (MODE == 0 || MODE == 3) {
                    u16* p = o_rm + (((size_t)(b*HH + h)) * TT + t0) * DD + d;
                    #pragma unroll
                    for (int r = 0; r < 4; ++r) p[(size_t)r * DD] = bv[r];
                }
                if (MODE == 1 || MODE == 3) {
                    const int ch = t0 >> 7, tc = t0 & (LCH-1);
                    u16* p = o_tr + (((size_t)((b*HH + h)*NCH + ch)) * DD + d) * LCH + tc;
                    *(ushort4*)p = make_ushort4(bv[0], bv[1], bv[2], bv[3]);
                }
            }
        }
    }
}

// Pass 1 (MFMA): per (b,h,chunk): S[d][e] = sum_t kt[d][t]*vt[e][t]; ksum[d]
// 1 wave per chunk, 4 waves per block.
__global__ __launch_bounds__(256)
void lca_pass1(const u16* __restrict__ kt, const u16* __restrict__ vt,
               float* __restrict__ Sloc, float* __restrict__ ksloc)
{
    const int wid = threadIdx.x >> 6, lane = threadIdx.x & 63;
    const int c = blockIdx.x * 4 + wid, bh = blockIdx.y;
    const u16* kg = kt + ((size_t)bh * NCH + c) * DD * LCH;
    const u16* vg = vt + ((size_t)bh * NCH + c) * DD * LCH;
    const int lr = lane & 15;
    const int lk = (lane >> 4) * 8;

    f32x4 acc[4][4];
    #pragma unroll
    for (int i = 0; i < 4; ++i)
        #pragma unroll
        for (int j = 0; j < 4; ++j)
            acc[i][j] = (f32x4){0.f, 0.f, 0.f, 0.f};

    #pragma unroll
    for (int ks = 0; ks < 4; ++ks) {
        const int k = ks*32 + lk;
        s16x8 af[4], bf[4];
        #pragma unroll
        for (int mi = 0; mi < 4; ++mi) af[mi] = *(const s16x8*)(kg + (size_t)(mi*16 + lr)*LCH + k);
        #pragma unroll
        for (int ni = 0; ni < 4; ++ni) bf[ni] = *(const s16x8*)(vg + (size_t)(ni*16 + lr)*LCH + k);
        #pragma unroll
        for (int mi = 0; mi < 4; ++mi)
            #pragma unroll
            for (int ni = 0; ni < 4; ++ni)
                acc[mi][ni] = __builtin_amdgcn_mfma_f32_16x16x32_bf16(af[mi], bf[ni], acc[mi][ni], 0, 0, 0);
    }

    float* So = Sloc + ((size_t)bh * NCH + c) * (DD*DD);
    #pragma unroll
    for (int mi = 0; mi < 4; ++mi)
        #pragma unroll
        for (int ni = 0; ni < 4; ++ni) {
            const int e = ni*16 + lr;
            #pragma unroll
            for (int r = 0; r < 4; ++r) {
                const int d = mi*16 + (lane >> 4)*4 + r;
                So[(size_t)d * DD + e] = acc[mi][ni][r];
            }
        }

    // ksum[d] = sum_t kt[d][t]
    float s = 0.0f;
    #pragma unroll
    for (int i = 0; i < 16; ++i) {
        s16x8 dv = *(const s16x8*)(kg + (size_t)lane * LCH + i*8);
        #pragma unroll
        for (int j = 0; j < 8; ++j) s += bf2f((u16)dv[j]);
    }
    ksloc[((size_t)bh * NCH + c) * DD + lane] = s;
}

// Pass 2: per (b,h): exclusive scan over chunks. Writes exclusive P transposed
// bf16 (pst[bh][c][e][d]), exclusive ksum fp32 (pksx), and final states to out.
__global__ __launch_bounds__(256)
void lca_pass2(const float* __restrict__ Sloc, const float* __restrict__ ksloc,
               u16* __restrict__ pst, float* __restrict__ pksx,
               float* __restrict__ out)
{
    const int bh = blockIdx.x;
    const int tid = threadIdx.x;
    const int d0 = (tid >> 4) * 4;
    const int e0 = (tid & 15) * 4;

    float run[4][4] = {};
    for (int c = 0; c < NCH; ++c) {
        u16* P = pst + ((size_t)bh * NCH + c) * (DD*DD);
        #pragma unroll
        for (int i = 0; i < 4; ++i)
            #pragma unroll
            for (int j = 0; j < 4; ++j)
                P[(size_t)(e0 + j) * DD + (d0 + i)] = bf16r(run[i][j]);
        const float* S = Sloc + ((size_t)bh * NCH + c) * (DD*DD);
        #pragma unroll
        for (int i = 0; i < 4; ++i) {
            const float4 t4 = *(const float4*)(S + (size_t)(d0 + i) * DD + e0);
            run[i][0] += t4.x; run[i][1] += t4.y; run[i][2] += t4.z; run[i][3] += t4.w;
        }
    }
    float* nkv = out + OUT_OFF_KV + (size_t)bh * (DD*DD);
    #pragma unroll
    for (int i = 0; i < 4; ++i)
        *(float4*)(nkv + (size_t)(d0 + i) * DD + e0) =
            make_float4(run[i][0], run[i][1], run[i][2], run[i][3]);

    if (tid < DD) {
        float r = 0.0f;
        for (int c = 0; c < NCH; ++c) {
            pksx[((size_t)bh * NCH + c) * DD + tid] = r;
            r += ksloc[((size_t)bh * NCH + c) * DD + tid];
        }
        out[OUT_OFF_KSUM + (size_t)bh * DD + tid] = r;
    }
}

// Pass 3 (MFMA): per (b,h,chunk):
//   scores = qp@kp^T (mask causal), den = rowsum + qp.pks + 1e-6
//   y = (qp@P^T + masked_scores@v) / den  -> ybf (B,T,C) bf16
__global__ __launch_bounds__(256)
void lca_pass3(const u16* __restrict__ qp, const u16* __restrict__ kp,
               const u16* __restrict__ vt, const u16* __restrict__ pst,
               const float* __restrict__ pksx, u16* __restrict__ ybf)
{
    __shared__ short SA[16384];   // qs [128][64] @byte 0; ks @byte 16384; As overlays [128][128]
    __shared__ short VS[8192];    // vt chunk [64][128]
    __shared__ short PS[4096];    // P^T [64][64]
    __shared__ float pks_s[DD];
    __shared__ float den_s[LCH];

    char* SAb = (char*)SA;
    char* VSb = (char*)VS;
    char* PSb = (char*)PS;

    const int c = blockIdx.x, bh = blockIdx.y;
    const int tid = threadIdx.x;
    const int lane = tid & 63, wid = tid >> 6;

    const u16* qg = qp + ((size_t)bh * TT + (size_t)c * LCH) * DD;
    const u16* kg = kp + ((size_t)bh * TT + (size_t)c * LCH) * DD;
    const u16* vg = vt + ((size_t)bh * NCH + c) * DD * LCH;
    const u16* pg = pst + ((size_t)bh * NCH + c) * (DD*DD);

    // stage (swizzled): qs, ks (rows 128B), vt (rows 256B), P^T (rows 128B)
    for (int i = tid; i < 1024; i += 256) {
        const int row = i >> 3, cc = i & 7;
        const s16x8 dv = *(const s16x8*)(qg + (size_t)row*DD + cc*8);
        *(s16x8*)(SAb + ((row*128 + cc*16) ^ ((row & 7) << 4))) = dv;
    }
    for (int i = tid; i < 1024; i += 256) {
        const int row = i >> 3, cc = i & 7;
        const s16x8 dv = *(const s16x8*)(kg + (size_t)row*DD + cc*8);
        *(s16x8*)(SAb + 16384 + ((row*128 + cc*16) ^ ((row & 7) << 4))) = dv;
    }
    for (int i = tid; i < 1024; i += 256) {
        const int row = i >> 4, cc = i & 15;
        const s16x8 dv = *(const s16x8*)(vg + (size_t)row*LCH + cc*8);
        *(s16x8*)(VSb + ((row*256 + cc*16) ^ ((row & 7) << 4))) = dv;
    }
    for (int i = tid; i < 512; i += 256) {
        const int row = i >> 3, cc = i & 7;
        const s16x8 dv = *(const s16x8*)(pg + (size_t)row*DD + cc*8);
        *(s16x8*)(PSb + ((row*128 + cc*16) ^ ((row & 7) << 4))) = dv;
    }
    if (tid < DD) pks_s[tid] = pksx[((size_t)bh * NCH + c) * DD + tid];
    __syncthreads();

    // den base: qp[t].pks + 1e-6
    if (tid < LCH) {
        const int t = tid;
        float s = 1e-6f;
        #pragma unroll
        for (int cc = 0; cc < 8; ++cc) {
            const s16x8 dv = *(const s16x8*)(SAb + ((t*128 + cc*16) ^ ((t & 7) << 4)));
            #pragma unroll
            for (int j = 0; j < 8; ++j) s += bf2f((u16)dv[j]) * pks_s[cc*8 + j];
        }
        den_s[t] = s;
    }

    const int wrow0 = wid * 32;
    const int lr = lane & 15;
    const int lg = lane >> 4;        // 0..3
    const int lk = lg * 8;

    // scores: 2x8 fragments, K=64
    f32x4 sacc[2][8];
    #pragma unroll
    for (int mi = 0; mi < 2; ++mi)
        #pragma unroll
        for (int ni = 0; ni < 8; ++ni)
            sacc[mi][ni] = (f32x4){0.f, 0.f, 0.f, 0.f};

    #pragma unroll
    for (int ks = 0; ks < 2; ++ks) {
        const int k2 = (ks*32 + lk) * 2;
        s16x8 af[2];
        #pragma unroll
        for (int mi = 0; mi < 2; ++mi) {
            const int row = wrow0 + mi*16 + lr;
            af[mi] = *(const s16x8*)(SAb + ((row*128 + k2) ^ ((row & 7) << 4)));
        }
        #pragma unroll
        for (int ni = 0; ni < 8; ++ni) {
            const int rowb = ni*16 + lr;
            const s16x8 bf = *(const s16x8*)(SAb + 16384 + ((rowb*128 + k2) ^ ((rowb & 7) << 4)));
            sacc[0][ni] = __builtin_amdgcn_mfma_f32_16x16x32_bf16(af[0], bf, sacc[0][ni], 0, 0, 0);
            sacc[1][ni] = __builtin_amdgcn_mfma_f32_16x16x32_bf16(af[1], bf, sacc[1][ni], 0, 0, 0);
        }
    }

    // pv-inter: y += qp @ P^T  (2x4 fragments, K=64)
    f32x4 pv[2][4];
    #pragma unroll
    for (int mi = 0; mi < 2; ++mi)
        #pragma unroll
        for (int ni = 0; ni < 4; ++ni)
            pv[mi][ni] = (f32x4){0.f, 0.f, 0.f, 0.f};

    #pragma unroll
    for (int ks = 0; ks < 2; ++ks) {
        const int k2 = (ks*32 + lk) * 2;
        s16x8 af[2];
        #pragma unroll
        for (int mi = 0; mi < 2; ++mi) {
            const int row = wrow0 + mi*16 + lr;
            af[mi] = *(const s16x8*)(SAb + ((row*128 + k2) ^ ((row & 7) << 4)));
        }
        #pragma unroll
        for (int ni = 0; ni < 4; ++ni) {
            const int rowb = ni*16 + lr;
            const s16x8 bf = *(const s16x8*)(PSb + ((rowb*128 + k2) ^ ((rowb & 7) << 4)));
            pv[0][ni] = __builtin_amdgcn_mfma_f32_16x16x32_bf16(af[0], bf, pv[0][ni], 0, 0, 0);
            pv[1][ni] = __builtin_amdgcn_mfma_f32_16x16x32_bf16(af[1], bf, pv[1][ni], 0, 0, 0);
        }
    }
    __syncthreads();   // all qs/ks reads done; As overlays them next

    // mask, accumulate den rowsums, write masked scores bf16 to As
    #pragma unroll
    for (int mi = 0; mi < 2; ++mi) {
        float dr[4] = {0.f, 0.f, 0.f, 0.f};
        #pragma unroll
        for (int ni = 0; ni < 8; ++ni) {
            const int tp = ni*16 + lr;
            #pragma unroll
            for (int r = 0; r < 4; ++r) {
                const int t = wrow0 + mi*16 + lg*4 + r;
                const float v = (tp <= t) ? sacc[mi][ni][r] : 0.f;
                dr[r] += v;
                *(u16*)(SAb + ((t*256 + tp*2) ^ ((t & 7) << 4))) = bf16r(v);
            }
        }
        #pragma unroll
        for (int r = 0; r < 4; ++r) {
            float s = dr[r];
            s += __shfl_xor(s, 1); s += __shfl_xor(s, 2);
            s += __shfl_xor(s, 4); s += __shfl_xor(s, 8);
            if (lr == 0) {
                const int t = wrow0 + mi*16 + lg*4 + r;
                den_s[t] += s;
            }
        }
    }
    __syncthreads();

    // pv-intra: y += masked_scores @ v  (K=128)
    #pragma unroll
    for (int ks = 0; ks < 4; ++ks) {
        const int k2 = (ks*32 + lk) * 2;
        s16x8 af[2];
        #pragma unroll
        for (int mi = 0; mi < 2; ++mi) {
            const int row = wrow0 + mi*16 + lr;
            af[mi] = *(const s16x8*)(SAb + ((row*256 + k2) ^ ((row & 7) << 4)));
        }
        #pragma unroll
        for (int ni = 0; ni < 4; ++ni) {
            const int rowb = ni*16 + lr;
            const s16x8 bf = *(const s16x8*)(VSb + ((rowb*256 + k2) ^ ((rowb & 7) << 4)));
            pv[0][ni] = __builtin_amdgcn_mfma_f32_16x16x32_bf16(af[0], bf, pv[0][ni], 0, 0, 0);
            pv[1][ni] = __builtin_amdgcn_mfma_f32_16x16x32_bf16(af[1], bf, pv[1][ni], 0, 0, 0);
        }
    }

    // epilogue: y/den -> ybf (B,T,C)
    const int b = bh >> 4, h = bh & (HH-1);
    #pragma unroll
    for (int mi = 0; mi < 2; ++mi)
        #pragma unroll
        for (int ni = 0; ni < 4; ++ni) {
            const int e = ni*16 + lr;
            #pragma unroll
            for (int r = 0; r < 4; ++r) {
                const int t = wrow0 + mi*16 + lg*4 + r;
                const float y = pv[mi][ni][r] / den_s[t];
                ybf[((size_t)(b*TT) + (size_t)c*LCH + t) * CC + h*DD + e] = bf16r(y);
            }
        }
}

extern "C" void kernel_launch(void* const* d_in, const int* in_sizes, int n_in,
                              void* d_out, int out_size, void* d_ws, size_t ws_size,
                              hipStream_t stream) {
    const float* x  = (const float*)d_in[0];
    const float* Wq = (const float*)d_in[1];
    const float* Wk = (const float*)d_in[2];
    const float* Wv = (const float*)d_in[3];
    const float* Wp = (const float*)d_in[4];
    const float* bp = (const float*)d_in[5];
    float* out = (float*)d_out;
    char* ws = (char*)d_ws;

    u16*   xbf  = (u16*)(ws + 0);            // 8 MB
    u16*   Wbf  = (u16*)(ws + (size_t)8*MB); // 2 MB (reused)
    u16*   qp   = (u16*)(ws + (size_t)10*MB);// 8 MB
    u16*   kp   = (u16*)(ws + (size_t)18*MB);// 8 MB
    u16*   kt   = (u16*)(ws + (size_t)26*MB);// 8 MB
    u16*   vt   = (u16*)(ws + (size_t)34*MB);// 8 MB
    u16*   ybf  = (u16*)(ws + (size_t)42*MB);// 8 MB
    float* Sl   = (float*)(ws + (size_t)50*MB);           // 8 MB
    float* ksl  = (float*)(ws + (size_t)58*MB);           // 128 KB
    float* pksx = (float*)(ws + (size_t)58*MB + 131072);  // 128 KB
    u16*   pst  = (u16*)(ws + (size_t)59*MB);             // 4 MB

    const dim3 gg(CC/128, MM/128);

    f2bf8<<<MM*CC/8/256, 256, 0, stream>>>(x, xbf, MM*CC/8);

    f2bf8<<<CC*CC/8/256, 256, 0, stream>>>(Wq, Wbf, CC*CC/8);
    lca_gemm_bf<0><<<gg, 256, 0, stream>>>(xbf, Wbf, nullptr, nullptr, qp, nullptr);
    f2bf8<<<CC*CC/8/256, 256, 0, stream>>>(Wk, Wbf, CC*CC/8);
    lca_gemm_bf<3><<<gg, 256, 0, stream>>>(xbf, Wbf, nullptr, nullptr, kp, kt);
    f2bf8<<<CC*CC/8/256, 256, 0, stream>>>(Wv, Wbf, CC*CC/8);
    lca_gemm_bf<1><<<gg, 256, 0, stream>>>(xbf, Wbf, nullptr, nullptr, nullptr, vt);

    lca_pass1<<<dim3(NCH/4, BHH), 256, 0, stream>>>(kt, vt, Sl, ksl);
    lca_pass2<<<BHH, 256, 0, stream>>>(Sl, ksl, pst, pksx, out);
    lca_pass3<<<dim3(NCH, BHH), 256, 0, stream>>>(qp, kp, vt, pst, pksx, ybf);

    f2bf8<<<CC*CC/8/256, 256, 0, stream>>>(Wp, Wbf, CC*CC/8);
    lca_gemm_bf<2><<<gg, 256, 0, stream>>>(ybf, Wbf, bp, out, nullptr, nullptr);
}

// Round 4
// 133.453 us; speedup vs baseline: 4.9218x; 1.2319x over previous
//
#include <hip/hip_runtime.h>
#include <math.h>

#define BB 2
#define TT 2048
#define CC 1024
#define HH 16
#define DD 64
#define MM (BB*TT)
#define LCH 128
#define NCH (TT/LCH)
#define BHH (BB*HH)

#define OUT_OFF_KV   4194304
#define OUT_OFF_KSUM 4325376
#define MB 1048576

typedef unsigned int u32;
typedef unsigned short u16;
typedef __attribute__((ext_vector_type(8))) short s16x8;
typedef __attribute__((ext_vector_type(8))) unsigned short us8;
typedef __attribute__((ext_vector_type(4))) float f32x4;

__device__ __forceinline__ float fmap(float x) {
    return x > 0.0f ? x + 1.0f : expf(x);
}
__device__ __forceinline__ u16 bf16r(float f) {
    u32 u = __float_as_uint(f);
    u += 0x7fffu + ((u >> 16) & 1u);
    return (u16)(u >> 16);
}
__device__ __forceinline__ float bf2f(u16 u) {
    return __uint_as_float(((u32)u) << 16);
}
__device__ __forceinline__ void gload16(const void* g, void* l) {
    __builtin_amdgcn_global_load_lds(
        (const __attribute__((address_space(1))) u32*)g,
        (__attribute__((address_space(3))) u32*)l, 16, 0, 0);
}

// Fused fp32->bf16 cast: x (524288 groups of 8) then Wq,Wk,Wv,Wp (131072 each)
// into xbf and contiguous Wbf[4*CC*CC].
__global__ __launch_bounds__(256)
void f2bf_all(const float* __restrict__ x,
              const float* __restrict__ Wq, const float* __restrict__ Wk,
              const float* __restrict__ Wv, const float* __restrict__ Wp,
              u16* __restrict__ xbf, u16* __restrict__ wbf)
{
    const int i = blockIdx.x * 256 + threadIdx.x;   // 0 .. 1048575
    const float* src;
    u16* dst;
    int off;
    if (i < 524288) {
        src = x; dst = xbf; off = i;
    } else {
        const int j = i - 524288;
        const int sel = j >> 17;          // 0..3
        off = j & 131071;
        src = (sel == 0) ? Wq : (sel == 1) ? Wk : (sel == 2) ? Wv : Wp;
        dst = wbf + ((size_t)sel << 20);  // sel * CC*CC elements / 1? (CC*CC = 1048576/... )
    }
    // note: CC*CC = 1048576 elements = 131072 groups; dst advanced in elements:
    // ((size_t)sel << 20) == sel * 1048576 elements. off is in groups of 8.
    const float4 a = ((const float4*)src)[off*2];
    const float4 b = ((const float4*)src)[off*2 + 1];
    us8 p;
    p[0]=bf16r(a.x); p[1]=bf16r(a.y); p[2]=bf16r(a.z); p[3]=bf16r(a.w);
    p[4]=bf16r(b.x); p[5]=bf16r(b.y); p[6]=bf16r(b.z); p[7]=bf16r(b.w);
    ((us8*)dst)[off] = p;
}

// Fused QKV GEMM: C[m,n] = sum_k x[m,k]*W[n,k], N = 3072 (Wq|Wk|Wv).
// sel = n>>10: 0 -> fmap -> qp rm (B,H,T,D); 1 -> fmap -> kp rm + kt tr;
//              2 -> plain -> vt tr.  tr layout: [bh][chunk][d][t_in_chunk]
__global__ __launch_bounds__(256)
void lca_gemm_qkv(const u16* __restrict__ A, const u16* __restrict__ Wall,
                  u16* __restrict__ qp, u16* __restrict__ kp,
                  u16* __restrict__ kt, u16* __restrict__ vt)
{
    __shared__ short As[128*32];
    __shared__ short Bs[128*32];
    const int tid  = threadIdx.x;
    const int lane = tid & 63;
    const int wid  = tid >> 6;
    const int bm0  = blockIdx.y * 128;
    const int bn0g = blockIdx.x * 128;       // 0..2944
    const int sel  = bn0g >> 10;             // 0,1,2
    const int nn0  = bn0g & (CC-1);          // col within selected W
    const u16* W = Wall + ((size_t)sel << 20);
    const int wm = wid >> 1, wn = wid & 1;

    const int rs = wid*32 + (lane >> 2);
    const int kc = (lane & 3) * 8;

    f32x4 acc[4][4];
    #pragma unroll
    for (int i = 0; i < 4; ++i)
        #pragma unroll
        for (int j = 0; j < 4; ++j)
            acc[i][j] = (f32x4){0.f, 0.f, 0.f, 0.f};

    const int rA = wm*64 + (lane & 15);
    const int rB = wn*64 + (lane & 15);
    const int kk = (lane >> 4) * 8;

    for (int k0 = 0; k0 < CC; k0 += 32) {
        #pragma unroll
        for (int j = 0; j < 2; ++j) {
            gload16(A + (size_t)(bm0 + rs + j*16) * CC + k0 + kc, &As[wid*1024 + j*512]);
            gload16(W + (size_t)(nn0 + rs + j*16) * CC + k0 + kc, &Bs[wid*1024 + j*512]);
        }
        __syncthreads();

        s16x8 af[4], bf[4];
        #pragma unroll
        for (int mi = 0; mi < 4; ++mi) af[mi] = *(const s16x8*)(&As[(rA + mi*16)*32 + kk]);
        #pragma unroll
        for (int ni = 0; ni < 4; ++ni) bf[ni] = *(const s16x8*)(&Bs[(rB + ni*16)*32 + kk]);
        #pragma unroll
        for (int mi = 0; mi < 4; ++mi)
            #pragma unroll
            for (int ni = 0; ni < 4; ++ni)
                acc[mi][ni] = __builtin_amdgcn_mfma_f32_16x16x32_bf16(af[mi], bf[ni], acc[mi][ni], 0, 0, 0);
        __syncthreads();
    }

    #pragma unroll
    for (int mi = 0; mi < 4; ++mi) {
        #pragma unroll
        for (int ni = 0; ni < 4; ++ni) {
            const int col = nn0 + wn*64 + ni*16 + (lane & 15);   // 0..1023
            const int rb  = bm0 + wm*64 + mi*16 + (lane >> 4)*4;
            const int h = col >> 6, d = col & (DD-1);
            const int b = rb >> 11, t0 = rb & (TT-1);
            u16 bv[4];
            #pragma unroll
            for (int r = 0; r < 4; ++r) {
                float val = acc[mi][ni][r];
                if (sel != 2) val = fmap(val);
                bv[r] = bf16r(val);
            }
            if (sel == 0) {
                u16* p = qp + (((size_t)(b*HH + h)) * TT + t0) * DD + d;
                #pragma unroll
                for (int r = 0; r < 4; ++r) p[(size_t)r * DD] = bv[r];
            } else {
                const int ch = t0 >> 7, tc = t0 & (LCH-1);
                u16* pt = (sel == 1 ? kt : vt)
                        + (((size_t)((b*HH + h)*NCH + ch)) * DD + d) * LCH + tc;
                *(ushort4*)pt = make_ushort4(bv[0], bv[1], bv[2], bv[3]);
                if (sel == 1) {
                    u16* p = kp + (((size_t)(b*HH + h)) * TT + t0) * DD + d;
                    #pragma unroll
                    for (int r = 0; r < 4; ++r) p[(size_t)r * DD] = bv[r];
                }
            }
        }
    }
}

// Final GEMM: out[m,n] = sum_k y[m,k]*Wp[n,k] + bp[n]. BM=128, BN=64 tile.
__global__ __launch_bounds__(256)
void lca_gemm_out(const u16* __restrict__ A, const u16* __restrict__ W,
                  const float* __restrict__ bias, float* __restrict__ out)
{
    __shared__ short As[128*32];
    __shared__ short Bs2[64*32];
    const int tid  = threadIdx.x;
    const int lane = tid & 63;
    const int wid  = tid >> 6;
    const int bm0 = blockIdx.y * 128;
    const int bn0 = blockIdx.x * 64;
    const int wm = wid >> 1, wn = wid & 1;

    const int rsA = wid*32 + (lane >> 2);
    const int rsB = wid*16 + (lane >> 2);
    const int kc  = (lane & 3) * 8;

    f32x4 acc[4][2];
    #pragma unroll
    for (int i = 0; i < 4; ++i)
        #pragma unroll
        for (int j = 0; j < 2; ++j)
            acc[i][j] = (f32x4){0.f, 0.f, 0.f, 0.f};

    const int rA = wm*64 + (lane & 15);
    const int rB = wn*32 + (lane & 15);
    const int kk = (lane >> 4) * 8;

    for (int k0 = 0; k0 < CC; k0 += 32) {
        #pragma unroll
        for (int j = 0; j < 2; ++j)
            gload16(A + (size_t)(bm0 + rsA + j*16) * CC + k0 + kc, &As[wid*1024 + j*512]);
        gload16(W + (size_t)(bn0 + rsB) * CC + k0 + kc, &Bs2[wid*512]);
        __syncthreads();

        s16x8 af[4], bf[2];
        #pragma unroll
        for (int mi = 0; mi < 4; ++mi) af[mi] = *(const s16x8*)(&As[(rA + mi*16)*32 + kk]);
        #pragma unroll
        for (int ni = 0; ni < 2; ++ni) bf[ni] = *(const s16x8*)(&Bs2[(rB + ni*16)*32 + kk]);
        #pragma unroll
        for (int mi = 0; mi < 4; ++mi)
            #pragma unroll
            for (int ni = 0; ni < 2; ++ni)
                acc[mi][ni] = __builtin_amdgcn_mfma_f32_16x16x32_bf16(af[mi], bf[ni], acc[mi][ni], 0, 0, 0);
        __syncthreads();
    }

    #pragma unroll
    for (int mi = 0; mi < 4; ++mi) {
        #pragma unroll
        for (int ni = 0; ni < 2; ++ni) {
            const int col = bn0 + wn*32 + ni*16 + (lane & 15);
            const int rb  = bm0 + wm*64 + mi*16 + (lane >> 4)*4;
            const float bb = bias[col];
            #pragma unroll
            for (int r = 0; r < 4; ++r)
                out[(size_t)(rb + r) * CC + col] = acc[mi][ni][r] + bb;
        }
    }
}

// Pass 1 (MFMA): per (b,h,chunk): S[d][e] = sum_t kt[d][t]*vt[e][t]; ksum[d]
__global__ __launch_bounds__(256)
void lca_pass1(const u16* __restrict__ kt, const u16* __restrict__ vt,
               float* __restrict__ Sloc, float* __restrict__ ksloc)
{
    const int wid = threadIdx.x >> 6, lane = threadIdx.x & 63;
    const int c = blockIdx.x * 4 + wid, bh = blockIdx.y;
    const u16* kg = kt + ((size_t)bh * NCH + c) * DD * LCH;
    const u16* vg = vt + ((size_t)bh * NCH + c) * DD * LCH;
    const int lr = lane & 15;
    const int lk = (lane >> 4) * 8;

    f32x4 acc[4][4];
    #pragma unroll
    for (int i = 0; i < 4; ++i)
        #pragma unroll
        for (int j = 0; j < 4; ++j)
            acc[i][j] = (f32x4){0.f, 0.f, 0.f, 0.f};

    #pragma unroll
    for (int ks = 0; ks < 4; ++ks) {
        const int k = ks*32 + lk;
        s16x8 af[4], bf[4];
        #pragma unroll
        for (int mi = 0; mi < 4; ++mi) af[mi] = *(const s16x8*)(kg + (size_t)(mi*16 + lr)*LCH + k);
        #pragma unroll
        for (int ni = 0; ni < 4; ++ni) bf[ni] = *(const s16x8*)(vg + (size_t)(ni*16 + lr)*LCH + k);
        #pragma unroll
        for (int mi = 0; mi < 4; ++mi)
            #pragma unroll
            for (int ni = 0; ni < 4; ++ni)
                acc[mi][ni] = __builtin_amdgcn_mfma_f32_16x16x32_bf16(af[mi], bf[ni], acc[mi][ni], 0, 0, 0);
    }

    float* So = Sloc + ((size_t)bh * NCH + c) * (DD*DD);
    #pragma unroll
    for (int mi = 0; mi < 4; ++mi)
        #pragma unroll
        for (int ni = 0; ni < 4; ++ni) {
            const int e = ni*16 + lr;
            #pragma unroll
            for (int r = 0; r < 4; ++r) {
                const int d = mi*16 + (lane >> 4)*4 + r;
                So[(size_t)d * DD + e] = acc[mi][ni][r];
            }
        }

    float s = 0.0f;
    #pragma unroll
    for (int i = 0; i < 16; ++i) {
        s16x8 dv = *(const s16x8*)(kg + (size_t)lane * LCH + i*8);
        #pragma unroll
        for (int j = 0; j < 8; ++j) s += bf2f((u16)dv[j]);
    }
    ksloc[((size_t)bh * NCH + c) * DD + lane] = s;
}

// Pass 2: per (b,h): exclusive scan over chunks -> pst (bf16, transposed),
// pksx (fp32), final states -> out.
__global__ __launch_bounds__(256)
void lca_pass2(const float* __restrict__ Sloc, const float* __restrict__ ksloc,
               u16* __restrict__ pst, float* __restrict__ pksx,
               float* __restrict__ out)
{
    const int bh = blockIdx.x;
    const int tid = threadIdx.x;
    const int d0 = (tid >> 4) * 4;
    const int e0 = (tid & 15) * 4;

    float run[4][4] = {};
    for (int c = 0; c < NCH; ++c) {
        u16* P = pst + ((size_t)bh * NCH + c) * (DD*DD);
        #pragma unroll
        for (int i = 0; i < 4; ++i)
            #pragma unroll
            for (int j = 0; j < 4; ++j)
                P[(size_t)(e0 + j) * DD + (d0 + i)] = bf16r(run[i][j]);
        const float* S = Sloc + ((size_t)bh * NCH + c) * (DD*DD);
        #pragma unroll
        for (int i = 0; i < 4; ++i) {
            const float4 t4 = *(const float4*)(S + (size_t)(d0 + i) * DD + e0);
            run[i][0] += t4.x; run[i][1] += t4.y; run[i][2] += t4.z; run[i][3] += t4.w;
        }
    }
    float* nkv = out + OUT_OFF_KV + (size_t)bh * (DD*DD);
    #pragma unroll
    for (int i = 0; i < 4; ++i)
        *(float4*)(nkv + (size_t)(d0 + i) * DD + e0) =
            make_float4(run[i][0], run[i][1], run[i][2], run[i][3]);

    if (tid < DD) {
        float r = 0.0f;
        for (int c = 0; c < NCH; ++c) {
            pksx[((size_t)bh * NCH + c) * DD + tid] = r;
            r += ksloc[((size_t)bh * NCH + c) * DD + tid];
        }
        out[OUT_OFF_KSUM + (size_t)bh * DD + tid] = r;
    }
}

// Pass 3 (MFMA): scores = qp@kp^T (causal), den = rowsum + qp.pks + 1e-6,
// y = (qp@P^T + masked_scores@v) / den -> ybf (B,T,C) bf16
__global__ __launch_bounds__(256)
void lca_pass3(const u16* __restrict__ qp, const u16* __restrict__ kp,
               const u16* __restrict__ vt, const u16* __restrict__ pst,
               const float* __restrict__ pksx, u16* __restrict__ ybf)
{
    __shared__ short SA[16384];   // qs [128][64] @0; ks @byte 16384; scores overlay [128][128]
    __shared__ short VS[8192];
    __shared__ short PS[4096];
    __shared__ float pks_s[DD];
    __shared__ float den_s[LCH];

    char* SAb = (char*)SA;
    char* VSb = (char*)VS;
    char* PSb = (char*)PS;

    const int c = blockIdx.x, bh = blockIdx.y;
    const int tid = threadIdx.x;
    const int lane = tid & 63, wid = tid >> 6;

    const u16* qg = qp + ((size_t)bh * TT + (size_t)c * LCH) * DD;
    const u16* kg = kp + ((size_t)bh * TT + (size_t)c * LCH) * DD;
    const u16* vg = vt + ((size_t)bh * NCH + c) * DD * LCH;
    const u16* pg = pst + ((size_t)bh * NCH + c) * (DD*DD);

    for (int i = tid; i < 1024; i += 256) {
        const int row = i >> 3, cc = i & 7;
        const s16x8 dv = *(const s16x8*)(qg + (size_t)row*DD + cc*8);
        *(s16x8*)(SAb + ((row*128 + cc*16) ^ ((row & 7) << 4))) = dv;
    }
    for (int i = tid; i < 1024; i += 256) {
        const int row = i >> 3, cc = i & 7;
        const s16x8 dv = *(const s16x8*)(kg + (size_t)row*DD + cc*8);
        *(s16x8*)(SAb + 16384 + ((row*128 + cc*16) ^ ((row & 7) << 4))) = dv;
    }
    for (int i = tid; i < 1024; i += 256) {
        const int row = i >> 4, cc = i & 15;
        const s16x8 dv = *(const s16x8*)(vg + (size_t)row*LCH + cc*8);
        *(s16x8*)(VSb + ((row*256 + cc*16) ^ ((row & 7) << 4))) = dv;
    }
    for (int i = tid; i < 512; i += 256) {
        const int row = i >> 3, cc = i & 7;
        const s16x8 dv = *(const s16x8*)(pg + (size_t)row*DD + cc*8);
        *(s16x8*)(PSb + ((row*128 + cc*16) ^ ((row & 7) << 4))) = dv;
    }
    if (tid < DD) pks_s[tid] = pksx[((size_t)bh * NCH + c) * DD + tid];
    __syncthreads();

    if (tid < LCH) {
        const int t = tid;
        float s = 1e-6f;
        #pragma unroll
        for (int cc = 0; cc < 8; ++cc) {
            const s16x8 dv = *(const s16x8*)(SAb + ((t*128 + cc*16) ^ ((t & 7) << 4)));
            #pragma unroll
            for (int j = 0; j < 8; ++j) s += bf2f((u16)dv[j]) * pks_s[cc*8 + j];
        }
        den_s[t] = s;
    }

    const int wrow0 = wid * 32;
    const int lr = lane & 15;
    const int lg = lane >> 4;
    const int lk = lg * 8;

    f32x4 sacc[2][8];
    #pragma unroll
    for (int mi = 0; mi < 2; ++mi)
        #pragma unroll
        for (int ni = 0; ni < 8; ++ni)
            sacc[mi][ni] = (f32x4){0.f, 0.f, 0.f, 0.f};

    #pragma unroll
    for (int ks = 0; ks < 2; ++ks) {
        const int k2 = (ks*32 + lk) * 2;
        s16x8 af[2];
        #pragma unroll
        for (int mi = 0; mi < 2; ++mi) {
            const int row = wrow0 + mi*16 + lr;
            af[mi] = *(const s16x8*)(SAb + ((row*128 + k2) ^ ((row & 7) << 4)));
        }
        #pragma unroll
        for (int ni = 0; ni < 8; ++ni) {
            const int rowb = ni*16 + lr;
            const s16x8 bf = *(const s16x8*)(SAb + 16384 + ((rowb*128 + k2) ^ ((rowb & 7) << 4)));
            sacc[0][ni] = __builtin_amdgcn_mfma_f32_16x16x32_bf16(af[0], bf, sacc[0][ni], 0, 0, 0);
            sacc[1][ni] = __builtin_amdgcn_mfma_f32_16x16x32_bf16(af[1], bf, sacc[1][ni], 0, 0, 0);
        }
    }

    f32x4 pv[2][4];
    #pragma unroll
    for (int mi = 0; mi < 2; ++mi)
        #pragma unroll
        for (int ni = 0; ni < 4; ++ni)
            pv[mi][ni] = (f32x4){0.f, 0.f, 0.f, 0.f};

    #pragma unroll
    for (int ks = 0; ks < 2; ++ks) {
        const int k2 = (ks*32 + lk) * 2;
        s16x8 af[2];
        #pragma unroll
        for (int mi = 0; mi < 2; ++mi) {
            const int row = wrow0 + mi*16 + lr;
            af[mi] = *(const s16x8*)(SAb + ((row*128 + k2) ^ ((row & 7) << 4)));
        }
        #pragma unroll
        for (int ni = 0; ni < 4; ++ni) {
            const int rowb = ni*16 + lr;
            const s16x8 bf = *(const s16x8*)(PSb + ((rowb*128 + k2) ^ ((rowb & 7) << 4)));
            pv[0][ni] = __builtin_amdgcn_mfma_f32_16x16x32_bf16(af[0], bf, pv[0][ni], 0, 0, 0);
            pv[1][ni] = __builtin_amdgcn_mfma_f32_16x16x32_bf16(af[1], bf, pv[1][ni], 0, 0, 0);
        }
    }
    __syncthreads();

    #pragma unroll
    for (int mi = 0; mi < 2; ++mi) {
        float dr[4] = {0.f, 0.f, 0.f, 0.f};
        #pragma unroll
        for (int ni = 0; ni < 8; ++ni) {
            const int tp = ni*16 + lr;
            #pragma unroll
            for (int r = 0; r < 4; ++r) {
                const int t = wrow0 + mi*16 + lg*4 + r;
                const float v = (tp <= t) ? sacc[mi][ni][r] : 0.f;
                dr[r] += v;
                *(u16*)(SAb + ((t*256 + tp*2) ^ ((t & 7) << 4))) = bf16r(v);
            }
        }
        #pragma unroll
        for (int r = 0; r < 4; ++r) {
            float s = dr[r];
            s += __shfl_xor(s, 1); s += __shfl_xor(s, 2);
            s += __shfl_xor(s, 4); s += __shfl_xor(s, 8);
            if (lr == 0) {
                const int t = wrow0 + mi*16 + lg*4 + r;
                den_s[t] += s;
            }
        }
    }
    __syncthreads();

    #pragma unroll
    for (int ks = 0; ks < 4; ++ks) {
        const int k2 = (ks*32 + lk) * 2;
        s16x8 af[2];
        #pragma unroll
        for (int mi = 0; mi < 2; ++mi) {
            const int row = wrow0 + mi*16 + lr;
            af[mi] = *(const s16x8*)(SAb + ((row*256 + k2) ^ ((row & 7) << 4)));
        }
        #pragma unroll
        for (int ni = 0; ni < 4; ++ni) {
            const int rowb = ni*16 + lr;
            const s16x8 bf = *(const s16x8*)(VSb + ((rowb*256 + k2) ^ ((rowb & 7) << 4)));
            pv[0][ni] = __builtin_amdgcn_mfma_f32_16x16x32_bf16(af[0], bf, pv[0][ni], 0, 0, 0);
            pv[1][ni] = __builtin_amdgcn_mfma_f32_16x16x32_bf16(af[1], bf, pv[1][ni], 0, 0, 0);
        }
    }

    const int b = bh >> 4, h = bh & (HH-1);
    #pragma unroll
    for (int mi = 0; mi < 2; ++mi)
        #pragma unroll
        for (int ni = 0; ni < 4; ++ni) {
            const int e = ni*16 + lr;
            #pragma unroll
            for (int r = 0; r < 4; ++r) {
                const int t = wrow0 + mi*16 + lg*4 + r;
                const float y = pv[mi][ni][r] / den_s[t];
                ybf[((size_t)(b*TT) + (size_t)c*LCH + t) * CC + h*DD + e] = bf16r(y);
            }
        }
}

extern "C" void kernel_launch(void* const* d_in, const int* in_sizes, int n_in,
                              void* d_out, int out_size, void* d_ws, size_t ws_size,
                              hipStream_t stream) {
    const float* x  = (const float*)d_in[0];
    const float* Wq = (const float*)d_in[1];
    const float* Wk = (const float*)d_in[2];
    const float* Wv = (const float*)d_in[3];
    const float* Wp = (const float*)d_in[4];
    const float* bp = (const float*)d_in[5];
    float* out = (float*)d_out;
    char* ws = (char*)d_ws;

    u16*   xbf  = (u16*)(ws + 0);                         // 8 MB
    u16*   Wbf  = (u16*)(ws + (size_t)8*MB);              // 8 MB (Wq|Wk|Wv|Wp)
    u16*   qp   = (u16*)(ws + (size_t)16*MB);             // 8 MB
    u16*   kp   = (u16*)(ws + (size_t)24*MB);             // 8 MB
    u16*   kt   = (u16*)(ws + (size_t)32*MB);             // 8 MB
    u16*   vt   = (u16*)(ws + (size_t)40*MB);             // 8 MB
    u16*   ybf  = (u16*)(ws + (size_t)48*MB);             // 8 MB
    float* Sl   = (float*)(ws + (size_t)56*MB);           // 8 MB
    float* ksl  = (float*)(ws + (size_t)64*MB);           // 128 KB
    float* pksx = (float*)(ws + (size_t)64*MB + 131072);  // 128 KB
    u16*   pst  = (u16*)(ws + (size_t)65*MB);             // 4 MB

    f2bf_all<<<4096, 256, 0, stream>>>(x, Wq, Wk, Wv, Wp, xbf, Wbf);

    lca_gemm_qkv<<<dim3(3*CC/128, MM/128), 256, 0, stream>>>(xbf, Wbf, qp, kp, kt, vt);

    lca_pass1<<<dim3(NCH/4, BHH), 256, 0, stream>>>(kt, vt, Sl, ksl);
    lca_pass2<<<BHH, 256, 0, stream>>>(Sl, ksl, pst, pksx, out);
    lca_pass3<<<dim3(NCH, BHH), 256, 0, stream>>>(qp, kp, vt, pst, pksx, ybf);

    lca_gemm_out<<<dim3(CC/64, MM/128), 256, 0, stream>>>(ybf, Wbf + ((size_t)3 << 20), bp, out);
}